// Round 14
// baseline (282.314 us; speedup 1.0000x reference)
//
#include <hip/hip_runtime.h>
#include <hip/hip_bf16.h>
#include <cstdint>
#include <cstddef>

#define B_ 16
#define T_ 2048
#define C_ 1024
#define H_ 256
#define KVB 32

typedef __attribute__((ext_vector_type(8))) short short8;
typedef __attribute__((ext_vector_type(4))) float f32x4;

// fp32 -> bf16 (RNE)
__device__ inline unsigned short f2bf(float f) {
    unsigned int u = __builtin_bit_cast(unsigned int, f);
    unsigned int r = (u + 0x7FFFu + ((u >> 16) & 1u)) >> 16;
    return (unsigned short)r;
}

// async global->LDS, 16B/lane; LDS dest wave-uniform base (+lane*16 by HW)
__device__ inline void glds16(const void* g, void* l) {
    __builtin_amdgcn_global_load_lds(
        (const __attribute__((address_space(1))) unsigned int*)g,
        (__attribute__((address_space(3))) unsigned int*)l, 16, 0, 0);
}

// ---------------------------------------------------------------------------
// Kernel 0: x fp32 -> bf16 (RNE)
// ---------------------------------------------------------------------------
__global__ __launch_bounds__(256) void xconv(const float* __restrict__ x,
                                             unsigned short* __restrict__ xb) {
    const int stride = gridDim.x * 256;
    const int n8 = B_ * T_ * C_ / 8;
    for (int i = blockIdx.x * 256 + threadIdx.x; i < n8; i += stride) {
        f32x4 v0 = *(const f32x4*)(x + (size_t)i * 8);
        f32x4 v1 = *(const f32x4*)(x + (size_t)i * 8 + 4);
        short8 o;
#pragma unroll
        for (int e = 0; e < 4; ++e) {
            o[e] = (short)f2bf(v0[e]);
            o[e + 4] = (short)f2bf(v1[e]);
        }
        *(short8*)(xb + (size_t)i * 8) = o;
    }
}

// ---------------------------------------------------------------------------
// Kernel 1: W [K][N] fp32 -> Wt [mat][N][K] bf16
// ---------------------------------------------------------------------------
__global__ void wconv(const float* __restrict__ Wq, const float* __restrict__ Wk,
                      const float* __restrict__ Wv, unsigned short* __restrict__ Wt) {
    int idx = blockIdx.x * 256 + threadIdx.x;
    const int per = C_ * H_;
    if (idx >= 3 * per) return;
    int mat = idx / per;
    int rem = idx - mat * per;
    int n = rem / C_;
    int k = rem - n * C_;
    const float* W = (mat == 0) ? Wq : (mat == 1) ? Wk : Wv;
    Wt[idx] = f2bf(W[(size_t)k * H_ + n]);
}

// ---------------------------------------------------------------------------
// Kernel 2: QKV GEMM (R11-proven). Block = 512 thr (8 waves = 4r x 2c) over
// 128r x 256c; wave tile 32r x 128c. W chunk staged via swizzled glds16, dbuf.
// ---------------------------------------------------------------------------
__global__ __launch_bounds__(512, 4) void qkv_gemm(
    const unsigned short* __restrict__ xb, const unsigned short* __restrict__ Wt,
    const float* __restrict__ bq, const float* __restrict__ bk,
    const float* __restrict__ bv,
    unsigned short* __restrict__ Qb, unsigned short* __restrict__ Kb,
    unsigned short* __restrict__ Vt)
{
    const int mat = blockIdx.y;
    const int tid = threadIdx.x;
    const int wid = tid >> 6;
    const int lane = tid & 63;
    const int c16 = lane & 15;
    const int g = lane >> 4;
    const int wr = wid >> 1, wc = wid & 1;
    const int rw = blockIdx.x * 128 + wr * 32;

    __shared__ __align__(16) unsigned short Wl[2][256 * 64];   // 2 x 32KB

    const char* wbB = (const char*)(Wt + (size_t)mat * H_ * C_);
    const unsigned short* xp0 = xb + (size_t)(rw + c16) * C_ + g * 8;
    const unsigned short* xp1 = xb + (size_t)(rw + 16 + c16) * C_ + g * 8;

    f32x4 acc[2][8];
#pragma unroll
    for (int rs = 0; rs < 2; ++rs)
#pragma unroll
        for (int nt = 0; nt < 8; ++nt) acc[rs][nt] = f32x4{0.f, 0.f, 0.f, 0.f};

#pragma unroll
    for (int j = 0; j < 4; ++j) {
        int off = j * 8192 + wid * 1024 + lane * 16;
        int row = off >> 7, colb = off & 127;
        glds16(wbB + (size_t)row * 2048 + (colb ^ ((row & 7) << 4)),
               (char*)&Wl[0][0] + j * 8192 + wid * 1024);
    }
    short8 xr0[2], xr1[2];
    xr0[0] = *(const short8*)(xp0);       xr0[1] = *(const short8*)(xp0 + 32);
    xr1[0] = *(const short8*)(xp1);       xr1[1] = *(const short8*)(xp1 + 32);
    __syncthreads();

    for (int ch = 0; ch < 16; ++ch) {
        const int cur = ch & 1;
        short8 af0[2] = {xr0[0], xr0[1]};
        short8 af1[2] = {xr1[0], xr1[1]};
        if (ch < 15) {
            xr0[0] = *(const short8*)(xp0 + (ch + 1) * 64);
            xr0[1] = *(const short8*)(xp0 + (ch + 1) * 64 + 32);
            xr1[0] = *(const short8*)(xp1 + (ch + 1) * 64);
            xr1[1] = *(const short8*)(xp1 + (ch + 1) * 64 + 32);
#pragma unroll
            for (int j = 0; j < 4; ++j) {
                int off = j * 8192 + wid * 1024 + lane * 16;
                int row = off >> 7, colb = off & 127;
                glds16(wbB + (size_t)row * 2048 + (ch + 1) * 128 + (colb ^ ((row & 7) << 4)),
                       (char*)&Wl[cur ^ 1][0] + j * 8192 + wid * 1024);
            }
        }
#pragma unroll
        for (int kk = 0; kk < 2; ++kk)
#pragma unroll
            for (int nt = 0; nt < 8; ++nt) {
                const int n = wc * 128 + nt * 16 + c16;
                short8 bfr = *(const short8*)((const char*)&Wl[cur][0] + n * 128 +
                                              ((kk * 64 + g * 16) ^ ((n & 7) << 4)));
                acc[0][nt] = __builtin_amdgcn_mfma_f32_16x16x32_bf16(af0[kk], bfr,
                                                                     acc[0][nt], 0, 0, 0);
                acc[1][nt] = __builtin_amdgcn_mfma_f32_16x16x32_bf16(af1[kk], bfr,
                                                                     acc[1][nt], 0, 0, 0);
            }
        __syncthreads();   // drains glds(ch+1), guards dbuf swap
    }

    const float* bias = (mat == 0) ? bq : (mat == 1) ? bk : bv;
#pragma unroll
    for (int rs = 0; rs < 2; ++rs)
#pragma unroll
        for (int nt = 0; nt < 8; ++nt) {
            const int n = wc * 128 + nt * 16 + c16;
            const float bias_v = bias[n];
#pragma unroll
            for (int rr = 0; rr < 4; ++rr) {
                const int rg = rw + rs * 16 + g * 4 + rr;
                const unsigned short hv = f2bf(acc[rs][nt][rr] + bias_v);
                if (mat == 0)      Qb[(size_t)rg * H_ + n] = hv;
                else if (mat == 1) Kb[(size_t)rg * H_ + n] = hv;
                else {
                    const int bb = rg >> 11, tt = rg & (T_ - 1);
                    Vt[((size_t)bb * H_ + n) * T_ + tt] = hv;
                }
            }
        }
}

// ---------------------------------------------------------------------------
// stage one KV tile (2 waves): K [32kv][256h] XOR-swz; V [256h][32kv] chunk-swz
// ---------------------------------------------------------------------------
__device__ inline void stage_tile(const char* kbB, const char* vtB, int sk,
                                  unsigned short* Kdst, unsigned short* Vdst,
                                  int wid, int lane) {
#pragma unroll
    for (int j = 0; j < 8; ++j) {
        int off = wid * 8192 + j * 1024 + lane * 16;
        int row = off >> 9, colb = off & 511;
        glds16(kbB + (size_t)(sk + row) * 512 + (colb ^ ((row & 7) << 4)),
               (char*)Kdst + wid * 8192 + j * 1024);
    }
#pragma unroll
    for (int j = 0; j < 8; ++j) {
        int h = wid * 128 + j * 16 + (lane >> 2);
        int slot = lane & 3;
        int c = slot ^ ((h >> 1) & 3);   // logical kv-chunk stored at this slot
        glds16(vtB + (size_t)h * 4096 + (size_t)(sk + c * 8) * 2,
               (char*)Vdst + wid * 8192 + j * 1024);
    }
}

// ---------------------------------------------------------------------------
// Kernel 3: flash attention, swapped-operand. Block = 2 waves x 32 q = 64 q.
// SINGLE-buffered K+V (36KB LDS) -> 4 blocks/CU x 2 waves = 8 waves/CU,
// combining the halved LDS-traffic shape (34 b128 reads / 64 MFMAs) with
// full TLP: stage->barrier->compute->barrier; other blocks hide the stalls.
// Residency-proof mapping: qi = 31-((bx>>2)&31) (constant across both
// slot-stride-128 and adjacent-packing co-residency), b = (bx&3)|((bx>>7)<<2).
// ---------------------------------------------------------------------------
__global__ __launch_bounds__(128) void attn(
    const unsigned short* __restrict__ Qb, const unsigned short* __restrict__ Kb,
    const unsigned short* __restrict__ Vt, float* __restrict__ out)
{
    const int bx = blockIdx.x;
    const int qi = 31 - ((bx >> 2) & 31);
    const int b = (bx & 3) | ((bx >> 7) << 2);
    const int q0 = qi * 64;
    const int ntiles = 2 * qi + 2;
    const int tid = threadIdx.x;
    const int wid = tid >> 6;                  // 0..1
    const int lane = tid & 63;
    const int c16 = lane & 15;
    const int g = lane >> 4;
    const int hsw = (c16 >> 1) & 3;
    const int qw = q0 + wid * 32;
    const int qg0 = qw + c16;
    const int qg1 = qw + 16 + c16;

    __shared__ __align__(16) unsigned short Kl[KVB * 256];      // 16KB
    __shared__ __align__(16) unsigned short Vl[256 * KVB];      // 16KB
    __shared__ __align__(16) unsigned short Pl[2][2][16 * 32];  // 4KB

    const char* kbB = (const char*)(Kb + (size_t)b * T_ * H_);
    const char* vtB = (const char*)(Vt + (size_t)b * H_ * T_);
    const float inv_scale = 0.022097086912079608f;   // 1/sqrt(2048)

    // Q fragments (B-operand), 2 subtiles
    short8 qf0[8], qf1[8];
    {
        const unsigned short* qp0 = Qb + (size_t)(b * T_ + qg0) * H_ + g * 8;
        const unsigned short* qp1 = Qb + (size_t)(b * T_ + qg1) * H_ + g * 8;
#pragma unroll
        for (int kc = 0; kc < 8; ++kc) {
            qf0[kc] = *(const short8*)(qp0 + kc * 32);
            qf1[kc] = *(const short8*)(qp1 + kc * 32);
        }
    }

    f32x4 o0[16], o1[16];
#pragma unroll
    for (int i = 0; i < 16; ++i) {
        o0[i] = f32x4{0.f, 0.f, 0.f, 0.f};
        o1[i] = f32x4{0.f, 0.f, 0.f, 0.f};
    }
    float m0 = -1e30f, m1 = -1e30f, ll0 = 0.f, ll1 = 0.f;

    for (int t = 0; t < ntiles; ++t) {
        const int sk = t * KVB;

        stage_tile(kbB, vtB, sk, &Kl[0], &Vl[0], wid, lane);
        __syncthreads();   // drains glds: K/V tile valid for all waves

        if (sk <= qw + 31) {   // wave-uniform: skip fully-masked tiles
            // ---- S^T = K Q^T (16 kf reads serve both subq) ----
            f32x4 sc0[2], sc1[2];
            __builtin_amdgcn_s_setprio(1);
#pragma unroll
            for (int ct = 0; ct < 2; ++ct) {
                f32x4 sa0 = f32x4{0.f, 0.f, 0.f, 0.f};
                f32x4 sa1 = f32x4{0.f, 0.f, 0.f, 0.f};
                const int row = ct * 16 + c16;
#pragma unroll
                for (int kc = 0; kc < 8; ++kc) {
                    short8 kf = *(const short8*)((const char*)&Kl[0] + row * 512 +
                                                 ((kc * 64 + g * 16) ^ ((row & 7) << 4)));
                    sa0 = __builtin_amdgcn_mfma_f32_16x16x32_bf16(kf, qf0[kc], sa0, 0, 0, 0);
                    sa1 = __builtin_amdgcn_mfma_f32_16x16x32_bf16(kf, qf1[kc], sa1, 0, 0, 0);
                }
                sc0[ct] = sa0; sc1[ct] = sa1;
            }
            __builtin_amdgcn_s_setprio(0);

            // ---- softmax, subq0 then subq1 (always-mask) ----
#pragma unroll
            for (int sq = 0; sq < 2; ++sq) {
                const int qg = sq ? qg1 : qg0;
                f32x4* sc = sq ? sc1 : sc0;
                f32x4* o  = sq ? o1 : o0;
                float& m  = sq ? m1 : m0;
                float& ll = sq ? ll1 : ll0;

                float p[8];
#pragma unroll
                for (int ct = 0; ct < 2; ++ct)
#pragma unroll
                    for (int rr = 0; rr < 4; ++rr) {
                        const int kv = sk + ct * 16 + g * 4 + rr;
                        float v = sc[ct][rr] * inv_scale;
                        p[ct * 4 + rr] = (kv > qg) ? -1e30f : v;
                    }
                float pmax = fmaxf(fmaxf(fmaxf(p[0], p[1]), fmaxf(p[2], p[3])),
                                   fmaxf(fmaxf(p[4], p[5]), fmaxf(p[6], p[7])));
                pmax = fmaxf(pmax, __shfl_xor(pmax, 16, 64));
                pmax = fmaxf(pmax, __shfl_xor(pmax, 32, 64));
                if (!__all(pmax <= m + 8.f)) {       // T13 defer-max
                    const float nm = fmaxf(m, pmax);
                    const float scf = __expf(m - nm);
                    ll *= scf;
#pragma unroll
                    for (int mt = 0; mt < 16; ++mt) {
                        o[mt][0] *= scf; o[mt][1] *= scf;
                        o[mt][2] *= scf; o[mt][3] *= scf;
                    }
                    m = nm;
                }
                float rsum = 0.f;
#pragma unroll
                for (int i = 0; i < 8; ++i) { p[i] = __expf(p[i] - m); rsum += p[i]; }
                rsum += __shfl_xor(rsum, 16, 64);
                rsum += __shfl_xor(rsum, 32, 64);
                ll += rsum;

                // P -> bf16 -> wave-local swizzled LDS (4 b32 writes)
                unsigned int* pw = (unsigned int*)&Pl[wid][sq][0];
#pragma unroll
                for (int ct = 0; ct < 2; ++ct)
#pragma unroll
                    for (int pr = 0; pr < 2; ++pr) {
                        int w = (ct * 8 + g * 2 + pr) ^ (hsw << 2);
                        unsigned int v = (unsigned int)f2bf(p[ct * 4 + pr * 2]) |
                                         ((unsigned int)f2bf(p[ct * 4 + pr * 2 + 1]) << 16);
                        pw[c16 * 16 + w] = v;
                    }
            }

            asm volatile("s_waitcnt lgkmcnt(0)" ::: "memory");
            __builtin_amdgcn_sched_barrier(0);
            short8 pb0 = *(const short8*)((const char*)&Pl[wid][0][0] + c16 * 64 +
                                          ((g ^ hsw) << 4));
            short8 pb1 = *(const short8*)((const char*)&Pl[wid][1][0] + c16 * 64 +
                                          ((g ^ hsw) << 4));

            // ---- O^T += V^T P^T (16 vf reads serve both subq) ----
            __builtin_amdgcn_s_setprio(1);
#pragma unroll
            for (int mt = 0; mt < 16; ++mt) {
                short8 vf = *(const short8*)((const char*)&Vl[0] +
                                             (mt * 16 + c16) * 64 + ((g ^ hsw) << 4));
                o0[mt] = __builtin_amdgcn_mfma_f32_16x16x32_bf16(vf, pb0, o0[mt], 0, 0, 0);
                o1[mt] = __builtin_amdgcn_mfma_f32_16x16x32_bf16(vf, pb1, o1[mt], 0, 0, 0);
            }
            __builtin_amdgcn_s_setprio(0);
        }

        __syncthreads();   // all waves done reading K/V -> safe to restage
    }

    // ---- epilogue: coalesced f32x4 stores ----
    const float i0 = 1.f / ll0, i1 = 1.f / ll1;
    float* op0 = out + (size_t)(b * T_ + qg0) * H_;
    float* op1 = out + (size_t)(b * T_ + qg1) * H_;
#pragma unroll
    for (int mt = 0; mt < 16; ++mt) {
        f32x4 v0, v1;
        v0[0] = o0[mt][0] * i0; v0[1] = o0[mt][1] * i0;
        v0[2] = o0[mt][2] * i0; v0[3] = o0[mt][3] * i0;
        v1[0] = o1[mt][0] * i1; v1[1] = o1[mt][1] * i1;
        v1[2] = o1[mt][2] * i1; v1[3] = o1[mt][3] * i1;
        *(f32x4*)(op0 + mt * 16 + g * 4) = v0;
        *(f32x4*)(op1 + mt * 16 + g * 4) = v1;
    }
}

// ---------------------------------------------------------------------------
extern "C" void kernel_launch(void* const* d_in, const int* in_sizes, int n_in,
                              void* d_out, int out_size, void* d_ws, size_t ws_size,
                              hipStream_t stream) {
    const float* x  = (const float*)d_in[0];
    const float* Wq = (const float*)d_in[1];
    const float* bq = (const float*)d_in[2];
    const float* Wk = (const float*)d_in[3];
    const float* bk = (const float*)d_in[4];
    const float* Wv = (const float*)d_in[5];
    const float* bv = (const float*)d_in[6];
    float* out = (float*)d_out;

    char* ws = (char*)d_ws;
    unsigned short* Wt = (unsigned short*)ws;                    // 1.5 MiB
    unsigned short* Qb = (unsigned short*)(ws + (2u  << 20));    // 16 MiB
    unsigned short* Kb = (unsigned short*)(ws + (18u << 20));    // 16 MiB
    unsigned short* Vt = (unsigned short*)(ws + (34u << 20));    // 16 MiB
    unsigned short* xb = (unsigned short*)(ws + (50u << 20));    // 64 MiB

    hipLaunchKernelGGL(xconv, dim3(2048), dim3(256), 0, stream, x, xb);
    hipLaunchKernelGGL(wconv, dim3((3 * C_ * H_ + 255) / 256), dim3(256), 0, stream,
                       Wq, Wk, Wv, Wt);
    hipLaunchKernelGGL(qkv_gemm, dim3(T_ * B_ / 128, 3), dim3(512), 0, stream,
                       xb, Wt, bq, bk, bv, Qb, Kb, Vt);
    hipLaunchKernelGGL(attn, dim3(512), dim3(128), 0, stream,
                       Qb, Kb, Vt, out);
}

// Round 15
// 232.605 us; speedup vs baseline: 1.2137x; 1.2137x over previous
//
#include <hip/hip_runtime.h>
#include <hip/hip_bf16.h>
#include <cstdint>
#include <cstddef>

#define B_ 16
#define T_ 2048
#define C_ 1024
#define H_ 256
#define KVB 32

typedef __attribute__((ext_vector_type(8))) short short8;
typedef __attribute__((ext_vector_type(4))) float f32x4;

// fp32 -> bf16 (RNE)
__device__ inline unsigned short f2bf(float f) {
    unsigned int u = __builtin_bit_cast(unsigned int, f);
    unsigned int r = (u + 0x7FFFu + ((u >> 16) & 1u)) >> 16;
    return (unsigned short)r;
}

// async global->LDS, 16B/lane; LDS dest wave-uniform base (+lane*16 by HW)
__device__ inline void glds16(const void* g, void* l) {
    __builtin_amdgcn_global_load_lds(
        (const __attribute__((address_space(1))) unsigned int*)g,
        (__attribute__((address_space(3))) unsigned int*)l, 16, 0, 0);
}

// ---------------------------------------------------------------------------
// Kernel 0: x fp32 -> bf16 (RNE)
// ---------------------------------------------------------------------------
__global__ __launch_bounds__(256) void xconv(const float* __restrict__ x,
                                             unsigned short* __restrict__ xb) {
    const int stride = gridDim.x * 256;
    const int n8 = B_ * T_ * C_ / 8;
    for (int i = blockIdx.x * 256 + threadIdx.x; i < n8; i += stride) {
        f32x4 v0 = *(const f32x4*)(x + (size_t)i * 8);
        f32x4 v1 = *(const f32x4*)(x + (size_t)i * 8 + 4);
        short8 o;
#pragma unroll
        for (int e = 0; e < 4; ++e) {
            o[e] = (short)f2bf(v0[e]);
            o[e + 4] = (short)f2bf(v1[e]);
        }
        *(short8*)(xb + (size_t)i * 8) = o;
    }
}

// ---------------------------------------------------------------------------
// Kernel 1: W [K][N] fp32 -> Wt [mat][N][K] bf16
// ---------------------------------------------------------------------------
__global__ void wconv(const float* __restrict__ Wq, const float* __restrict__ Wk,
                      const float* __restrict__ Wv, unsigned short* __restrict__ Wt) {
    int idx = blockIdx.x * 256 + threadIdx.x;
    const int per = C_ * H_;
    if (idx >= 3 * per) return;
    int mat = idx / per;
    int rem = idx - mat * per;
    int n = rem / C_;
    int k = rem - n * C_;
    const float* W = (mat == 0) ? Wq : (mat == 1) ? Wk : Wv;
    Wt[idx] = f2bf(W[(size_t)k * H_ + n]);
}

// ---------------------------------------------------------------------------
// Kernel 2: QKV GEMM (R11-proven). Block = 512 thr (8 waves = 4r x 2c) over
// 128r x 256c; wave tile 32r x 128c. W chunk staged via swizzled glds16, dbuf.
// ---------------------------------------------------------------------------
__global__ __launch_bounds__(512, 4) void qkv_gemm(
    const unsigned short* __restrict__ xb, const unsigned short* __restrict__ Wt,
    const float* __restrict__ bq, const float* __restrict__ bk,
    const float* __restrict__ bv,
    unsigned short* __restrict__ Qb, unsigned short* __restrict__ Kb,
    unsigned short* __restrict__ Vt)
{
    const int mat = blockIdx.y;
    const int tid = threadIdx.x;
    const int wid = tid >> 6;
    const int lane = tid & 63;
    const int c16 = lane & 15;
    const int g = lane >> 4;
    const int wr = wid >> 1, wc = wid & 1;
    const int rw = blockIdx.x * 128 + wr * 32;

    __shared__ __align__(16) unsigned short Wl[2][256 * 64];   // 2 x 32KB

    const char* wbB = (const char*)(Wt + (size_t)mat * H_ * C_);
    const unsigned short* xp0 = xb + (size_t)(rw + c16) * C_ + g * 8;
    const unsigned short* xp1 = xb + (size_t)(rw + 16 + c16) * C_ + g * 8;

    f32x4 acc[2][8];
#pragma unroll
    for (int rs = 0; rs < 2; ++rs)
#pragma unroll
        for (int nt = 0; nt < 8; ++nt) acc[rs][nt] = f32x4{0.f, 0.f, 0.f, 0.f};

#pragma unroll
    for (int j = 0; j < 4; ++j) {
        int off = j * 8192 + wid * 1024 + lane * 16;
        int row = off >> 7, colb = off & 127;
        glds16(wbB + (size_t)row * 2048 + (colb ^ ((row & 7) << 4)),
               (char*)&Wl[0][0] + j * 8192 + wid * 1024);
    }
    short8 xr0[2], xr1[2];
    xr0[0] = *(const short8*)(xp0);       xr0[1] = *(const short8*)(xp0 + 32);
    xr1[0] = *(const short8*)(xp1);       xr1[1] = *(const short8*)(xp1 + 32);
    __syncthreads();

    for (int ch = 0; ch < 16; ++ch) {
        const int cur = ch & 1;
        short8 af0[2] = {xr0[0], xr0[1]};
        short8 af1[2] = {xr1[0], xr1[1]};
        if (ch < 15) {
            xr0[0] = *(const short8*)(xp0 + (ch + 1) * 64);
            xr0[1] = *(const short8*)(xp0 + (ch + 1) * 64 + 32);
            xr1[0] = *(const short8*)(xp1 + (ch + 1) * 64);
            xr1[1] = *(const short8*)(xp1 + (ch + 1) * 64 + 32);
#pragma unroll
            for (int j = 0; j < 4; ++j) {
                int off = j * 8192 + wid * 1024 + lane * 16;
                int row = off >> 7, colb = off & 127;
                glds16(wbB + (size_t)row * 2048 + (ch + 1) * 128 + (colb ^ ((row & 7) << 4)),
                       (char*)&Wl[cur ^ 1][0] + j * 8192 + wid * 1024);
            }
        }
#pragma unroll
        for (int kk = 0; kk < 2; ++kk)
#pragma unroll
            for (int nt = 0; nt < 8; ++nt) {
                const int n = wc * 128 + nt * 16 + c16;
                short8 bfr = *(const short8*)((const char*)&Wl[cur][0] + n * 128 +
                                              ((kk * 64 + g * 16) ^ ((n & 7) << 4)));
                acc[0][nt] = __builtin_amdgcn_mfma_f32_16x16x32_bf16(af0[kk], bfr,
                                                                     acc[0][nt], 0, 0, 0);
                acc[1][nt] = __builtin_amdgcn_mfma_f32_16x16x32_bf16(af1[kk], bfr,
                                                                     acc[1][nt], 0, 0, 0);
            }
        __syncthreads();   // drains glds(ch+1), guards dbuf swap
    }

    const float* bias = (mat == 0) ? bq : (mat == 1) ? bk : bv;
#pragma unroll
    for (int rs = 0; rs < 2; ++rs)
#pragma unroll
        for (int nt = 0; nt < 8; ++nt) {
            const int n = wc * 128 + nt * 16 + c16;
            const float bias_v = bias[n];
#pragma unroll
            for (int rr = 0; rr < 4; ++rr) {
                const int rg = rw + rs * 16 + g * 4 + rr;
                const unsigned short hv = f2bf(acc[rs][nt][rr] + bias_v);
                if (mat == 0)      Qb[(size_t)rg * H_ + n] = hv;
                else if (mat == 1) Kb[(size_t)rg * H_ + n] = hv;
                else {
                    const int bb = rg >> 11, tt = rg & (T_ - 1);
                    Vt[((size_t)bb * H_ + n) * T_ + tt] = hv;
                }
            }
        }
}

// ---------------------------------------------------------------------------
// stage one KV tile, split across 4 waves (each stages 4KB of K + 4KB of V):
// K [32kv][256h] XOR-swz; V [256h][32kv] chunk-XOR-swz.
// ---------------------------------------------------------------------------
__device__ inline void stage_tile4(const char* kbB, const char* vtB, int sk,
                                   unsigned short* Kdst, unsigned short* Vdst,
                                   int wid, int lane) {
#pragma unroll
    for (int j = 0; j < 4; ++j) {
        int off = wid * 4096 + j * 1024 + lane * 16;
        int row = off >> 9, colb = off & 511;
        glds16(kbB + (size_t)(sk + row) * 512 + (colb ^ ((row & 7) << 4)),
               (char*)Kdst + off - lane * 16);
    }
#pragma unroll
    for (int j = 0; j < 4; ++j) {
        int off = wid * 4096 + j * 1024 + lane * 16;
        int h = off >> 6;                 // 64B per h-row
        int slot = lane & 3;
        int c = slot ^ ((h >> 1) & 3);    // logical kv-chunk at this slot
        glds16(vtB + (size_t)h * 4096 + (size_t)(sk + c * 8) * 2,
               (char*)Vdst + off - lane * 16);
    }
}

// ---------------------------------------------------------------------------
// Kernel 3: flash attention with KV-SPLIT. Block = 4 waves x 16 q = 64 q,
// handling HALF of its q-tile's causal kv range (qi+1 tiles of 32).
// Grid 1024 = 4 blocks/CU (36.8KB LDS, single-buffered K+V) = 16 waves/CU.
// qi quadruple mapping: co-resident slots {bx, bx+256, bx+512, bx+768} get
// qi = {2r, 31-2r, 2r+1, 30-2r} -> every CU sums to exactly 66 tiles.
// Outputs raw-O + (m,l) partials; `combine` merges the two halves.
// ---------------------------------------------------------------------------
__global__ __launch_bounds__(256) void attn(
    const unsigned short* __restrict__ Qb, const unsigned short* __restrict__ Kb,
    const unsigned short* __restrict__ Vt, float* __restrict__ Opart,
    float2* __restrict__ ml)
{
    const int bx = blockIdx.x;                 // 0..1023
    const int r = bx >> 5;                     // qi-group 0..31
    const int tq = r >> 3, rq = r & 7;
    const int qi = (tq == 0) ? 2 * rq : (tq == 1) ? 31 - 2 * rq
                 : (tq == 2) ? 2 * rq + 1 : 30 - 2 * rq;
    const int half = (bx >> 4) & 1;
    const int b = bx & 15;
    const int q0 = qi * 64;
    const int t0 = half ? (qi + 1) : 0;        // each half: qi+1 tiles
    const int t1 = t0 + qi + 1;
    const int tid = threadIdx.x;
    const int wid = tid >> 6;                  // 0..3
    const int lane = tid & 63;
    const int c16 = lane & 15;
    const int g = lane >> 4;
    const int hsw = (c16 >> 1) & 3;
    const int qw = q0 + wid * 16;
    const int qg = qw + c16;                   // this lane's q row

    __shared__ __align__(16) unsigned short Kl[KVB * 256];   // 16KB
    __shared__ __align__(16) unsigned short Vl[256 * KVB];   // 16KB
    __shared__ __align__(16) unsigned short Pl[4][16 * 32];  // 4KB

    const char* kbB = (const char*)(Kb + (size_t)b * T_ * H_);
    const char* vtB = (const char*)(Vt + (size_t)b * H_ * T_);
    const float inv_scale = 0.022097086912079608f;   // 1/sqrt(2048)

    // Q fragments (B-operand of swapped QK^T)
    short8 qf[8];
    const unsigned short* qp = Qb + (size_t)(b * T_ + qg) * H_ + g * 8;
#pragma unroll
    for (int kc = 0; kc < 8; ++kc) qf[kc] = *(const short8*)(qp + kc * 32);

    f32x4 o[16];
#pragma unroll
    for (int i = 0; i < 16; ++i) o[i] = f32x4{0.f, 0.f, 0.f, 0.f};
    float m = -1e30f, ll = 0.f;

    for (int t = t0; t < t1; ++t) {
        const int sk = t * KVB;

        stage_tile4(kbB, vtB, sk, &Kl[0], &Vl[0], wid, lane);
        __syncthreads();   // drains glds: K/V tile valid

        if (sk <= qw + 15) {   // wave-uniform: skip fully-masked tiles
            // ---- S^T = K Q^T : lane holds S[q=qg][kv=sk+ct*16+g*4+rr] ----
            f32x4 sc[2];
            __builtin_amdgcn_s_setprio(1);
#pragma unroll
            for (int ct = 0; ct < 2; ++ct) {
                f32x4 sa = f32x4{0.f, 0.f, 0.f, 0.f};
                const int row = ct * 16 + c16;
#pragma unroll
                for (int kc = 0; kc < 8; ++kc) {
                    short8 kf = *(const short8*)((const char*)&Kl[0] + row * 512 +
                                                 ((kc * 64 + g * 16) ^ ((row & 7) << 4)));
                    sa = __builtin_amdgcn_mfma_f32_16x16x32_bf16(kf, qf[kc], sa, 0, 0, 0);
                }
                sc[ct] = sa;
            }
            __builtin_amdgcn_s_setprio(0);

            // ---- mask + scale ----
            float p[8];
#pragma unroll
            for (int ct = 0; ct < 2; ++ct)
#pragma unroll
                for (int rr = 0; rr < 4; ++rr) {
                    const int kv = sk + ct * 16 + g * 4 + rr;
                    float v = sc[ct][rr] * inv_scale;
                    p[ct * 4 + rr] = (kv > qg) ? -1e30f : v;
                }

            // ---- per-lane softmax (2 cross-lane ops) ----
            float pmax = fmaxf(fmaxf(fmaxf(p[0], p[1]), fmaxf(p[2], p[3])),
                               fmaxf(fmaxf(p[4], p[5]), fmaxf(p[6], p[7])));
            pmax = fmaxf(pmax, __shfl_xor(pmax, 16, 64));
            pmax = fmaxf(pmax, __shfl_xor(pmax, 32, 64));
            if (!__all(pmax <= m + 8.f)) {       // T13 defer-max
                const float nm = fmaxf(m, pmax);
                const float scf = __expf(m - nm);
                ll *= scf;
#pragma unroll
                for (int mt = 0; mt < 16; ++mt) {
                    o[mt][0] *= scf; o[mt][1] *= scf;
                    o[mt][2] *= scf; o[mt][3] *= scf;
                }
                m = nm;
            }
            float rsum = 0.f;
#pragma unroll
            for (int i = 0; i < 8; ++i) { p[i] = __expf(p[i] - m); rsum += p[i]; }
            rsum += __shfl_xor(rsum, 16, 64);
            rsum += __shfl_xor(rsum, 32, 64);
            ll += rsum;

            // ---- P -> bf16 -> wave-local swizzled LDS (4 b32 writes) ----
            unsigned int* pw = (unsigned int*)&Pl[wid][0];
#pragma unroll
            for (int ct = 0; ct < 2; ++ct)
#pragma unroll
                for (int pr = 0; pr < 2; ++pr) {
                    int w = (ct * 8 + g * 2 + pr) ^ (hsw << 2);
                    unsigned int v = (unsigned int)f2bf(p[ct * 4 + pr * 2]) |
                                     ((unsigned int)f2bf(p[ct * 4 + pr * 2 + 1]) << 16);
                    pw[c16 * 16 + w] = v;
                }
            asm volatile("s_waitcnt lgkmcnt(0)" ::: "memory");
            __builtin_amdgcn_sched_barrier(0);
            short8 pb = *(const short8*)((const char*)&Pl[wid][0] + c16 * 64 +
                                         ((g ^ hsw) << 4));

            // ---- O^T += V^T P^T ----
            __builtin_amdgcn_s_setprio(1);
#pragma unroll
            for (int mt = 0; mt < 16; ++mt) {
                short8 vf = *(const short8*)((const char*)&Vl[0] +
                                             (mt * 16 + c16) * 64 + ((g ^ hsw) << 4));
                o[mt] = __builtin_amdgcn_mfma_f32_16x16x32_bf16(vf, pb, o[mt], 0, 0, 0);
            }
            __builtin_amdgcn_s_setprio(0);
        }

        __syncthreads();   // all waves done reading K/V -> safe to restage
    }

    // ---- epilogue: raw partials (no division) ----
    float* op = Opart + ((size_t)(half * 16 + b) * T_ + qg) * H_;
#pragma unroll
    for (int mt = 0; mt < 16; ++mt)
        *(f32x4*)(op + mt * 16 + g * 4) = o[mt];
    if (g == 0)
        ml[(size_t)(half * 16 + b) * T_ + qg] = make_float2(m, ll);
}

// ---------------------------------------------------------------------------
// Kernel 4: combine the two kv-halves per q-row (flash merge).
// ---------------------------------------------------------------------------
__global__ __launch_bounds__(256) void combine(const float* __restrict__ Opart,
                                               const float2* __restrict__ ml,
                                               float* __restrict__ out) {
    const int stride = gridDim.x * 256;
    const int n4 = B_ * T_ * (H_ / 4);          // 2,097,152 f32x4 units
    for (int u = blockIdx.x * 256 + threadIdx.x; u < n4; u += stride) {
        const int row = u >> 6;
        const int c4 = (u & 63) << 2;
        const float2 a = ml[row];
        const float2 bb = ml[B_ * T_ + row];
        const float mx = fmaxf(a.x, bb.x);
        const float w0 = __expf(a.x - mx);
        const float w1 = __expf(bb.x - mx);
        const float inv = 1.f / (a.y * w0 + bb.y * w1);
        f32x4 o0 = *(const f32x4*)(Opart + (size_t)row * H_ + c4);
        f32x4 o1 = *(const f32x4*)(Opart + (size_t)(B_ * T_) * H_ +
                                   (size_t)row * H_ + c4);
        f32x4 ov;
#pragma unroll
        for (int e = 0; e < 4; ++e) ov[e] = (o0[e] * w0 + o1[e] * w1) * inv;
        *(f32x4*)(out + (size_t)row * H_ + c4) = ov;
    }
}

// ---------------------------------------------------------------------------
extern "C" void kernel_launch(void* const* d_in, const int* in_sizes, int n_in,
                              void* d_out, int out_size, void* d_ws, size_t ws_size,
                              hipStream_t stream) {
    const float* x  = (const float*)d_in[0];
    const float* Wq = (const float*)d_in[1];
    const float* bq = (const float*)d_in[2];
    const float* Wk = (const float*)d_in[3];
    const float* bk = (const float*)d_in[4];
    const float* Wv = (const float*)d_in[5];
    const float* bv = (const float*)d_in[6];
    float* out = (float*)d_out;

    char* ws = (char*)d_ws;
    unsigned short* Wt = (unsigned short*)ws;                    // 1.5 MiB @0
    float2* ml         = (float2*)(ws + 1536u * 1024u);          // 512 KiB @1.5M
    unsigned short* Qb = (unsigned short*)(ws + (2u  << 20));    // 16 MiB
    unsigned short* Kb = (unsigned short*)(ws + (18u << 20));    // 16 MiB
    unsigned short* Vt = (unsigned short*)(ws + (34u << 20));    // 16 MiB
    unsigned short* xb = (unsigned short*)(ws + (50u << 20));    // 64 MiB
    float* Opart       = (float*)(ws + (50u << 20));             // reuses xb (dead after qkv)

    hipLaunchKernelGGL(xconv, dim3(2048), dim3(256), 0, stream, x, xb);
    hipLaunchKernelGGL(wconv, dim3((3 * C_ * H_ + 255) / 256), dim3(256), 0, stream,
                       Wq, Wk, Wv, Wt);
    hipLaunchKernelGGL(qkv_gemm, dim3(T_ * B_ / 128, 3), dim3(512), 0, stream,
                       xb, Wt, bq, bk, bv, Qb, Kb, Vt);
    hipLaunchKernelGGL(attn, dim3(1024), dim3(256), 0, stream,
                       Qb, Kb, Vt, Opart, ml);
    hipLaunchKernelGGL(combine, dim3(2048), dim3(256), 0, stream,
                       Opart, ml, out);
}

// Round 16
// 228.377 us; speedup vs baseline: 1.2362x; 1.0185x over previous
//
#include <hip/hip_runtime.h>
#include <hip/hip_bf16.h>
#include <cstdint>
#include <cstddef>

#define B_ 16
#define T_ 2048
#define C_ 1024
#define H_ 256
#define KVB 32

typedef __attribute__((ext_vector_type(8))) short short8;
typedef __attribute__((ext_vector_type(4))) float f32x4;

// fp32 -> bf16 (RNE)
__device__ inline unsigned short f2bf(float f) {
    unsigned int u = __builtin_bit_cast(unsigned int, f);
    unsigned int r = (u + 0x7FFFu + ((u >> 16) & 1u)) >> 16;
    return (unsigned short)r;
}

// async global->LDS, 16B/lane; LDS dest wave-uniform base (+lane*16 by HW)
__device__ inline void glds16(const void* g, void* l) {
    __builtin_amdgcn_global_load_lds(
        (const __attribute__((address_space(1))) unsigned int*)g,
        (__attribute__((address_space(3))) unsigned int*)l, 16, 0, 0);
}

// ---------------------------------------------------------------------------
// Kernel 0: x fp32 -> bf16 (RNE)
// ---------------------------------------------------------------------------
__global__ __launch_bounds__(256) void xconv(const float* __restrict__ x,
                                             unsigned short* __restrict__ xb) {
    const int stride = gridDim.x * 256;
    const int n8 = B_ * T_ * C_ / 8;
    for (int i = blockIdx.x * 256 + threadIdx.x; i < n8; i += stride) {
        f32x4 v0 = *(const f32x4*)(x + (size_t)i * 8);
        f32x4 v1 = *(const f32x4*)(x + (size_t)i * 8 + 4);
        short8 o;
#pragma unroll
        for (int e = 0; e < 4; ++e) {
            o[e] = (short)f2bf(v0[e]);
            o[e + 4] = (short)f2bf(v1[e]);
        }
        *(short8*)(xb + (size_t)i * 8) = o;
    }
}

// ---------------------------------------------------------------------------
// Kernel 1: W [K][N] fp32 -> Wt [mat][N][K] bf16
// ---------------------------------------------------------------------------
__global__ void wconv(const float* __restrict__ Wq, const float* __restrict__ Wk,
                      const float* __restrict__ Wv, unsigned short* __restrict__ Wt) {
    int idx = blockIdx.x * 256 + threadIdx.x;
    const int per = C_ * H_;
    if (idx >= 3 * per) return;
    int mat = idx / per;
    int rem = idx - mat * per;
    int n = rem / C_;
    int k = rem - n * C_;
    const float* W = (mat == 0) ? Wq : (mat == 1) ? Wk : Wv;
    Wt[idx] = f2bf(W[(size_t)k * H_ + n]);
}

// ---------------------------------------------------------------------------
// Kernel 2: QKV GEMM (R11-proven). Block = 512 thr (8 waves = 4r x 2c) over
// 128r x 256c; wave tile 32r x 128c. W chunk staged via swizzled glds16, dbuf.
// ---------------------------------------------------------------------------
__global__ __launch_bounds__(512, 4) void qkv_gemm(
    const unsigned short* __restrict__ xb, const unsigned short* __restrict__ Wt,
    const float* __restrict__ bq, const float* __restrict__ bk,
    const float* __restrict__ bv,
    unsigned short* __restrict__ Qb, unsigned short* __restrict__ Kb,
    unsigned short* __restrict__ Vt)
{
    const int mat = blockIdx.y;
    const int tid = threadIdx.x;
    const int wid = tid >> 6;
    const int lane = tid & 63;
    const int c16 = lane & 15;
    const int g = lane >> 4;
    const int wr = wid >> 1, wc = wid & 1;
    const int rw = blockIdx.x * 128 + wr * 32;

    __shared__ __align__(16) unsigned short Wl[2][256 * 64];   // 2 x 32KB

    const char* wbB = (const char*)(Wt + (size_t)mat * H_ * C_);
    const unsigned short* xp0 = xb + (size_t)(rw + c16) * C_ + g * 8;
    const unsigned short* xp1 = xb + (size_t)(rw + 16 + c16) * C_ + g * 8;

    f32x4 acc[2][8];
#pragma unroll
    for (int rs = 0; rs < 2; ++rs)
#pragma unroll
        for (int nt = 0; nt < 8; ++nt) acc[rs][nt] = f32x4{0.f, 0.f, 0.f, 0.f};

#pragma unroll
    for (int j = 0; j < 4; ++j) {
        int off = j * 8192 + wid * 1024 + lane * 16;
        int row = off >> 7, colb = off & 127;
        glds16(wbB + (size_t)row * 2048 + (colb ^ ((row & 7) << 4)),
               (char*)&Wl[0][0] + j * 8192 + wid * 1024);
    }
    short8 xr0[2], xr1[2];
    xr0[0] = *(const short8*)(xp0);       xr0[1] = *(const short8*)(xp0 + 32);
    xr1[0] = *(const short8*)(xp1);       xr1[1] = *(const short8*)(xp1 + 32);
    __syncthreads();

    for (int ch = 0; ch < 16; ++ch) {
        const int cur = ch & 1;
        short8 af0[2] = {xr0[0], xr0[1]};
        short8 af1[2] = {xr1[0], xr1[1]};
        if (ch < 15) {
            xr0[0] = *(const short8*)(xp0 + (ch + 1) * 64);
            xr0[1] = *(const short8*)(xp0 + (ch + 1) * 64 + 32);
            xr1[0] = *(const short8*)(xp1 + (ch + 1) * 64);
            xr1[1] = *(const short8*)(xp1 + (ch + 1) * 64 + 32);
#pragma unroll
            for (int j = 0; j < 4; ++j) {
                int off = j * 8192 + wid * 1024 + lane * 16;
                int row = off >> 7, colb = off & 127;
                glds16(wbB + (size_t)row * 2048 + (ch + 1) * 128 + (colb ^ ((row & 7) << 4)),
                       (char*)&Wl[cur ^ 1][0] + j * 8192 + wid * 1024);
            }
        }
#pragma unroll
        for (int kk = 0; kk < 2; ++kk)
#pragma unroll
            for (int nt = 0; nt < 8; ++nt) {
                const int n = wc * 128 + nt * 16 + c16;
                short8 bfr = *(const short8*)((const char*)&Wl[cur][0] + n * 128 +
                                              ((kk * 64 + g * 16) ^ ((n & 7) << 4)));
                acc[0][nt] = __builtin_amdgcn_mfma_f32_16x16x32_bf16(af0[kk], bfr,
                                                                     acc[0][nt], 0, 0, 0);
                acc[1][nt] = __builtin_amdgcn_mfma_f32_16x16x32_bf16(af1[kk], bfr,
                                                                     acc[1][nt], 0, 0, 0);
            }
        __syncthreads();   // drains glds(ch+1), guards dbuf swap
    }

    const float* bias = (mat == 0) ? bq : (mat == 1) ? bk : bv;
#pragma unroll
    for (int rs = 0; rs < 2; ++rs)
#pragma unroll
        for (int nt = 0; nt < 8; ++nt) {
            const int n = wc * 128 + nt * 16 + c16;
            const float bias_v = bias[n];
#pragma unroll
            for (int rr = 0; rr < 4; ++rr) {
                const int rg = rw + rs * 16 + g * 4 + rr;
                const unsigned short hv = f2bf(acc[rs][nt][rr] + bias_v);
                if (mat == 0)      Qb[(size_t)rg * H_ + n] = hv;
                else if (mat == 1) Kb[(size_t)rg * H_ + n] = hv;
                else {
                    const int bb = rg >> 11, tt = rg & (T_ - 1);
                    Vt[((size_t)bb * H_ + n) * T_ + tt] = hv;
                }
            }
        }
}

// ---------------------------------------------------------------------------
// stage one KV tile, split across 4 waves (each stages 4KB of K + 4KB of V):
// K [32kv][256h] XOR-swz; V [256h][32kv] chunk-XOR-swz.
// ---------------------------------------------------------------------------
__device__ inline void stage_tile4(const char* kbB, const char* vtB, int sk,
                                   unsigned short* Kdst, unsigned short* Vdst,
                                   int wid, int lane) {
#pragma unroll
    for (int j = 0; j < 4; ++j) {
        int off = wid * 4096 + j * 1024 + lane * 16;
        int row = off >> 9, colb = off & 511;
        glds16(kbB + (size_t)(sk + row) * 512 + (colb ^ ((row & 7) << 4)),
               (char*)Kdst + off - lane * 16);
    }
#pragma unroll
    for (int j = 0; j < 4; ++j) {
        int off = wid * 4096 + j * 1024 + lane * 16;
        int h = off >> 6;                 // 64B per h-row
        int slot = lane & 3;
        int c = slot ^ ((h >> 1) & 3);    // logical kv-chunk at this slot
        glds16(vtB + (size_t)h * 4096 + (size_t)(sk + c * 8) * 2,
               (char*)Vdst + off - lane * 16);
    }
}

// ---------------------------------------------------------------------------
// Kernel 3: flash attention, kv-split with EXACT-LENGTH PAIRING.
// Block = 4 waves x 16 q = 64 q. Every block runs exactly 33 kv-tiles:
//   A(p): [first half of q-tile p] + [second half of q-tile 31-p]
//   B(p): [first half of q-tile 31-p] + [second half of q-tile p]
// (lengths (p+1)+(32-p) = 33 and (32-p)+(p+1) = 33.)
// Grid 512 x 256 thr, dbuf K+V (68.8KB LDS) -> 2 blocks/CU = 8 waves/CU,
// constant for the whole kernel (zero tail, zero stragglers).
// b = bx&15 pins each batch's 4MB K+V to one XCD L2. ph -> Opart slot ph.
// ---------------------------------------------------------------------------
__global__ __launch_bounds__(256) void attn(
    const unsigned short* __restrict__ Qb, const unsigned short* __restrict__ Kb,
    const unsigned short* __restrict__ Vt, float* __restrict__ Opart,
    float2* __restrict__ ml)
{
    const int bx = blockIdx.x;                 // 0..511
    const int b = bx & 15;
    const int ab = (bx >> 4) & 1;              // 0 = A, 1 = B
    const int p = bx >> 5;                     // 0..15
    int qt[2], ts[2], te[2];
    if (ab == 0) {
        qt[0] = p;        ts[0] = 0;          te[0] = p + 1;
        qt[1] = 31 - p;   ts[1] = 32 - p;     te[1] = 64 - 2 * p;
    } else {
        qt[0] = 31 - p;   ts[0] = 0;          te[0] = 32 - p;
        qt[1] = p;        ts[1] = p + 1;      te[1] = 2 * p + 2;
    }
    const int tid = threadIdx.x;
    const int wid = tid >> 6;                  // 0..3
    const int lane = tid & 63;
    const int c16 = lane & 15;
    const int g = lane >> 4;
    const int hsw = (c16 >> 1) & 3;

    __shared__ __align__(16) unsigned short Kl[2][KVB * 256];   // 2 x 16KB
    __shared__ __align__(16) unsigned short Vl[2][256 * KVB];   // 2 x 16KB
    __shared__ __align__(16) unsigned short Pl[4][16 * 32];     // 4KB

    const char* kbB = (const char*)(Kb + (size_t)b * T_ * H_);
    const char* vtB = (const char*)(Vt + (size_t)b * H_ * T_);
    const float inv_scale = 0.022097086912079608f;   // 1/sqrt(2048)

#pragma unroll 1
    for (int ph = 0; ph < 2; ++ph) {
        const int qw = qt[ph] * 64 + wid * 16;
        const int qg = qw + c16;               // this lane's q row

        // Q fragments (B-operand of swapped QK^T)
        short8 qf[8];
        const unsigned short* qp = Qb + (size_t)(b * T_ + qg) * H_ + g * 8;
#pragma unroll
        for (int kc = 0; kc < 8; ++kc) qf[kc] = *(const short8*)(qp + kc * 32);

        f32x4 o[16];
#pragma unroll
        for (int i = 0; i < 16; ++i) o[i] = f32x4{0.f, 0.f, 0.f, 0.f};
        float m = -1e30f, ll = 0.f;

        stage_tile4(kbB, vtB, ts[ph] * KVB, &Kl[0][0], &Vl[0][0], wid, lane);
        __syncthreads();

        for (int t = ts[ph]; t < te[ph]; ++t) {
            const int cur = (t - ts[ph]) & 1;
            const int sk = t * KVB;

            if (t + 1 < te[ph])
                stage_tile4(kbB, vtB, sk + KVB, &Kl[cur ^ 1][0], &Vl[cur ^ 1][0],
                            wid, lane);

            if (sk <= qw + 15) {   // wave-uniform: skip fully-masked tiles
                // ---- S^T = K Q^T : lane holds S[q=qg][kv=sk+ct*16+g*4+rr] ----
                f32x4 sc[2];
                __builtin_amdgcn_s_setprio(1);
#pragma unroll
                for (int ct = 0; ct < 2; ++ct) {
                    f32x4 sa = f32x4{0.f, 0.f, 0.f, 0.f};
                    const int row = ct * 16 + c16;
#pragma unroll
                    for (int kc = 0; kc < 8; ++kc) {
                        short8 kf = *(const short8*)((const char*)&Kl[cur][0] + row * 512 +
                                                     ((kc * 64 + g * 16) ^ ((row & 7) << 4)));
                        sa = __builtin_amdgcn_mfma_f32_16x16x32_bf16(kf, qf[kc], sa, 0, 0, 0);
                    }
                    sc[ct] = sa;
                }
                __builtin_amdgcn_s_setprio(0);

                // ---- mask + scale ----
                float pv[8];
#pragma unroll
                for (int ct = 0; ct < 2; ++ct)
#pragma unroll
                    for (int rr = 0; rr < 4; ++rr) {
                        const int kv = sk + ct * 16 + g * 4 + rr;
                        float v = sc[ct][rr] * inv_scale;
                        pv[ct * 4 + rr] = (kv > qg) ? -1e30f : v;
                    }

                // ---- per-lane softmax (2 cross-lane ops) ----
                float pmax = fmaxf(fmaxf(fmaxf(pv[0], pv[1]), fmaxf(pv[2], pv[3])),
                                   fmaxf(fmaxf(pv[4], pv[5]), fmaxf(pv[6], pv[7])));
                pmax = fmaxf(pmax, __shfl_xor(pmax, 16, 64));
                pmax = fmaxf(pmax, __shfl_xor(pmax, 32, 64));
                if (!__all(pmax <= m + 8.f)) {       // T13 defer-max
                    const float nm = fmaxf(m, pmax);
                    const float scf = __expf(m - nm);
                    ll *= scf;
#pragma unroll
                    for (int mt = 0; mt < 16; ++mt) {
                        o[mt][0] *= scf; o[mt][1] *= scf;
                        o[mt][2] *= scf; o[mt][3] *= scf;
                    }
                    m = nm;
                }
                float rsum = 0.f;
#pragma unroll
                for (int i = 0; i < 8; ++i) { pv[i] = __expf(pv[i] - m); rsum += pv[i]; }
                rsum += __shfl_xor(rsum, 16, 64);
                rsum += __shfl_xor(rsum, 32, 64);
                ll += rsum;

                // ---- P -> bf16 -> wave-local swizzled LDS (4 b32 writes) ----
                unsigned int* pw = (unsigned int*)&Pl[wid][0];
#pragma unroll
                for (int ct = 0; ct < 2; ++ct)
#pragma unroll
                    for (int pr = 0; pr < 2; ++pr) {
                        int w = (ct * 8 + g * 2 + pr) ^ (hsw << 2);
                        unsigned int v = (unsigned int)f2bf(pv[ct * 4 + pr * 2]) |
                                         ((unsigned int)f2bf(pv[ct * 4 + pr * 2 + 1]) << 16);
                        pw[c16 * 16 + w] = v;
                    }
                asm volatile("s_waitcnt lgkmcnt(0)" ::: "memory");
                __builtin_amdgcn_sched_barrier(0);
                short8 pb = *(const short8*)((const char*)&Pl[wid][0] + c16 * 64 +
                                             ((g ^ hsw) << 4));

                // ---- O^T += V^T P^T ----
                __builtin_amdgcn_s_setprio(1);
#pragma unroll
                for (int mt = 0; mt < 16; ++mt) {
                    short8 vf = *(const short8*)((const char*)&Vl[cur][0] +
                                                 (mt * 16 + c16) * 64 + ((g ^ hsw) << 4));
                    o[mt] = __builtin_amdgcn_mfma_f32_16x16x32_bf16(vf, pb, o[mt], 0, 0, 0);
                }
                __builtin_amdgcn_s_setprio(0);
            }

            __syncthreads();   // drains (t+1) glds; guards dbuf + Pl reuse
        }

        // ---- epilogue: raw partials, slot = ph ----
        float* op = Opart + ((size_t)(ph * 16 + b) * T_ + qg) * H_;
#pragma unroll
        for (int mt = 0; mt < 16; ++mt)
            *(f32x4*)(op + mt * 16 + g * 4) = o[mt];
        if (g == 0)
            ml[(size_t)(ph * 16 + b) * T_ + qg] = make_float2(m, ll);
    }
}

// ---------------------------------------------------------------------------
// Kernel 4: combine the two kv-halves per q-row (flash merge).
// ---------------------------------------------------------------------------
__global__ __launch_bounds__(256) void combine(const float* __restrict__ Opart,
                                               const float2* __restrict__ ml,
                                               float* __restrict__ out) {
    const int stride = gridDim.x * 256;
    const int n4 = B_ * T_ * (H_ / 4);
    for (int u = blockIdx.x * 256 + threadIdx.x; u < n4; u += stride) {
        const int row = u >> 6;
        const int c4 = (u & 63) << 2;
        const float2 a = ml[row];
        const float2 bb = ml[B_ * T_ + row];
        const float mx = fmaxf(a.x, bb.x);
        const float w0 = __expf(a.x - mx);
        const float w1 = __expf(bb.x - mx);
        const float inv = 1.f / (a.y * w0 + bb.y * w1);
        f32x4 o0 = *(const f32x4*)(Opart + (size_t)row * H_ + c4);
        f32x4 o1 = *(const f32x4*)(Opart + (size_t)(B_ * T_) * H_ +
                                   (size_t)row * H_ + c4);
        f32x4 ov;
#pragma unroll
        for (int e = 0; e < 4; ++e) ov[e] = (o0[e] * w0 + o1[e] * w1) * inv;
        *(f32x4*)(out + (size_t)row * H_ + c4) = ov;
    }
}

// ---------------------------------------------------------------------------
extern "C" void kernel_launch(void* const* d_in, const int* in_sizes, int n_in,
                              void* d_out, int out_size, void* d_ws, size_t ws_size,
                              hipStream_t stream) {
    const float* x  = (const float*)d_in[0];
    const float* Wq = (const float*)d_in[1];
    const float* bq = (const float*)d_in[2];
    const float* Wk = (const float*)d_in[3];
    const float* bk = (const float*)d_in[4];
    const float* Wv = (const float*)d_in[5];
    const float* bv = (const float*)d_in[6];
    float* out = (float*)d_out;

    char* ws = (char*)d_ws;
    unsigned short* Wt = (unsigned short*)ws;                    // 1.5 MiB @0
    float2* ml         = (float2*)(ws + 1536u * 1024u);          // 512 KiB @1.5M
    unsigned short* Qb = (unsigned short*)(ws + (2u  << 20));    // 16 MiB
    unsigned short* Kb = (unsigned short*)(ws + (18u << 20));    // 16 MiB
    unsigned short* Vt = (unsigned short*)(ws + (34u << 20));    // 16 MiB
    unsigned short* xb = (unsigned short*)(ws + (50u << 20));    // 64 MiB
    float* Opart       = (float*)(ws + (50u << 20));             // reuses xb (dead after qkv)

    hipLaunchKernelGGL(xconv, dim3(2048), dim3(256), 0, stream, x, xb);
    hipLaunchKernelGGL(wconv, dim3((3 * C_ * H_ + 255) / 256), dim3(256), 0, stream,
                       Wq, Wk, Wv, Wt);
    hipLaunchKernelGGL(qkv_gemm, dim3(T_ * B_ / 128, 3), dim3(512), 0, stream,
                       xb, Wt, bq, bk, bv, Qb, Kb, Vt);
    hipLaunchKernelGGL(attn, dim3(512), dim3(256), 0, stream,
                       Qb, Kb, Vt, Opart, ml);
    hipLaunchKernelGGL(combine, dim3(2048), dim3(256), 0, stream,
                       Opart, ml, out);
}